// Round 14
// baseline (608.144 us; speedup 1.0000x reference)
//
#include <hip/hip_runtime.h>

// NormEMAVectorQuantizer on MI355X (gfx950)
// N=8192 tokens, C=32, K=8192 codes, B=32, H*W=256.
// R14: R13's single-kernel fusion WITHOUT hipLaunchCooperativeKernel (R13's
// coop launch silently failed -> kernel never ran; Output-2 fingerprint
// matched the R0 empty stub). Plain launch, 512 blocks, hand-rolled
// generation-tagged grid barrier on device-scope atomics (+caps: a broken
// barrier fails gracefully instead of hanging). __launch_bounds__(256,4)
// guarantees >=4 blocks/CU capacity (1024 slots >= 512 blocks) -> all blocks
// co-resident regardless of packing. 7 phases = R12's verified kernels:
// prep+zero | MFMA sweep->pmax | rescan+exact fp32 rescore | z_q+loss+ids |
// bins scan | place | EMA update. Certificate: bf16 dot err <= 2*2^-9 =
// 0.0078 < eps=0.01 for unit rows -> every possible fp32 argmax (incl. ties)
// is exact-rescored; (8191-code) key = numpy lowest-index tie-break.
//
// Outputs (float32, concatenated):
//   [0 .. 262144)        z_q_out [B,C,H,W]
//   [262144]             loss (scalar)
//   [262145 .. 270337)   token_ids [B,H,W] as float
//   [270337 .. 532481)   new_embedding [K,C]
//   [532481 .. 540673)   new_cluster_sizes [K]

#define NTOK   8192
#define NCODE  8192
#define CDIM   32
#define HW     256
#define DECAYF 0.99f
#define EPSF   0.01f

#define OUT_ZQ   0
#define OUT_LOSS 262144
#define OUT_IDS  262145
#define OUT_EMB  270337
#define OUT_CS   532481

// workspace byte offsets
#define WS_ZN     0u        // zn row-major [N,C] f32   = 1048576
#define WS_ZNBF   1048576u  // bf16 [N,C]               = 524288
#define WS_EBF    1572864u  // bf16 [K,C]               = 524288
#define WS_PMAX   2097152u  // f32 [32][N]              = 1048576
#define WS_PACK   3145728u  // u64 [N]                  = 65536
#define WS_BINS   3211264u  // i32 [K]                  = 32768
#define WS_LOSSP  3244032u  // f32 [64]                 = 256
#define WS_IDS    3244288u  // i32 [N]
#define WS_POS    3277056u  // i32 [N]
#define WS_OFFS   3309824u  // i32 [K]
#define WS_SORTED 3342592u  // i32 [N]
#define WS_ARRIVE 3375360u  // i32 [512] barrier arrivals (0xAA poison < any g)
#define WS_GEN    3377408u  // i32 generation            (end 3377412)

#define CHUNK  256
#define NCHUNK (NCODE / CHUNK)  // 32
#define TILES  (CHUNK / 16)     // 16
#define NBLK   512

typedef __attribute__((ext_vector_type(8))) short bf16x8;
typedef __attribute__((ext_vector_type(4))) float f32x4;

__device__ inline unsigned short f2bf(float x) {
    unsigned u = __float_as_uint(x);
    return (unsigned short)((u + 0x7FFFu + ((u >> 16) & 1u)) >> 16);
}
__device__ inline unsigned fmap(float s) {   // monotonic f32 -> u32
    unsigned u = __float_as_uint(s);
    return (u & 0x80000000u) ? ~u : (u | 0x80000000u);
}

// grid barrier, generation g (1..6). Device-scope atomics (cross-XCD safe);
// 0xAAAAAAAA poison is negative -> below every g. Spin caps: fail, don't hang.
__device__ inline void gbar(int g, int* arrive, int* gen) {
    __syncthreads();
    __threadfence();                              // my writes visible first
    if (blockIdx.x == 0) {
        if (threadIdx.x == 0) atomicExch(&arrive[0], g);
        int a = threadIdx.x, b = threadIdx.x + 256;
        for (int i = 0; i < 10000000; ++i)
            if (atomicAdd(&arrive[a], 0) >= g) break;
        for (int i = 0; i < 10000000; ++i)
            if (atomicAdd(&arrive[b], 0) >= g) break;
        __syncthreads();
        if (threadIdx.x == 0) atomicExch(gen, g);
    } else {
        if (threadIdx.x == 0) {
            atomicExch(&arrive[blockIdx.x], g);
            for (int i = 0; i < 10000000; ++i)
                if (atomicAdd(gen, 0) >= g) break;
        }
        __syncthreads();
    }
    __threadfence();                              // acquire others' writes
    __syncthreads();
}

__global__ __launch_bounds__(256, 4) void k_all(
    const float* __restrict__ z, const float* __restrict__ emb,
    const float* __restrict__ cs, float* __restrict__ out,
    float* __restrict__ zn, unsigned short* __restrict__ znbf,
    unsigned short* __restrict__ ebf, float* __restrict__ pmax,
    unsigned long long* __restrict__ packed, int* __restrict__ bins,
    float* __restrict__ loss_part, int* __restrict__ ids,
    int* __restrict__ pos, int* __restrict__ offs, int* __restrict__ sorted,
    int* __restrict__ arrive, int* __restrict__ gen) {
    __shared__ unsigned short lbs[CHUNK * CDIM];  // 16 KiB
    __shared__ float lf[256];
    __shared__ float ls4[4];
    __shared__ int wtot[4];

    int bid = blockIdx.x, t = threadIdx.x;
    int wave = t >> 6, lane = t & 63;
    int col = lane & 15, quad = lane >> 4;

    // ---------------- phase 0: prep + zero ----------------
    if (bid < 32) {                               // token norm -> zn, znbf
        int n = bid * 256 + t;
        int b = n >> 8, hw = n & 255;
        const float* zp = z + (size_t)b * (CDIM * HW) + hw;
        float v[CDIM];
        float ss = 0.f;
#pragma unroll
        for (int c = 0; c < CDIM; ++c) {
            float tv = zp[c * HW];                // coalesced per c
            v[c] = tv;
            ss += tv * tv;
        }
        float d = fmaxf(sqrtf(ss), 1e-12f);
        float* o = zn + (size_t)n * CDIM;
        unsigned short* ob = znbf + (size_t)n * CDIM;
#pragma unroll
        for (int c = 0; c < CDIM; ++c) {
            float tv = v[c] / d;
            o[c] = tv;
            ob[c] = f2bf(tv);
        }
    } else if (bid < 160) {                       // emb -> ebf
        int base = (bid - 32) * 2048 + t * 8;
        const float4* s = (const float4*)(emb + base);
        float4 x4 = s[0], y4 = s[1];
        ushort4 u0 = {f2bf(x4.x), f2bf(x4.y), f2bf(x4.z), f2bf(x4.w)};
        ushort4 u1 = {f2bf(y4.x), f2bf(y4.y), f2bf(y4.z), f2bf(y4.w)};
        *(ushort4*)(ebf + base) = u0;
        *(ushort4*)(ebf + base + 4) = u1;
    } else if (bid < 164) {                       // zero packed
        int base = (bid - 160) * 2048 + t;
#pragma unroll
        for (int j = 0; j < 8; ++j) packed[base + j * 256] = 0ull;
    } else if (bid < 168) {                       // zero bins
        int base = (bid - 164) * 2048 + t;
#pragma unroll
        for (int j = 0; j < 8; ++j) bins[base + j * 256] = 0;
    } else if (bid == 168) {
        if (t < 64) loss_part[t] = 0.f;
    }
    gbar(1, arrive, gen);

    // ---------------- phase 1: MFMA sweep -> pmax (2 chunks/block) -----------
    int x = bid & 31, grp = bid >> 5;             // x = token-block; grp -> 2 y's
    int wtok = x * 256 + wave * 64;
    bf16x8 a[4];                                  // A-frags: depend on x only
#pragma unroll
    for (int f = 0; f < 4; ++f)
        a[f] = *(const bf16x8*)(znbf + (size_t)(wtok + f * 16 + col) * CDIM + quad * 8);
    const bf16x8* bl = (const bf16x8*)lbs;
    const f32x4 zero4 = {0.f, 0.f, 0.f, 0.f};

    for (int i = 0; i < 2; ++i) {
        int y = grp * 2 + i, kbase = y * CHUNK;
        __syncthreads();                          // lbs/lf reuse guard
        {
            const float4* src = (const float4*)(ebf + (size_t)kbase * CDIM);
            float4* dst = (float4*)lbs;
#pragma unroll
            for (int j = 0; j < 4; ++j) dst[t + j * 256] = src[t + j * 256];
        }
        __syncthreads();
        float m[4][4];
#pragma unroll
        for (int f = 0; f < 4; ++f)
#pragma unroll
            for (int r = 0; r < 4; ++r) m[f][r] = -1e30f;
        for (int tt = 0; tt < TILES; ++tt) {
            bf16x8 b = bl[(tt * 16 + col) * 4 + quad];
#pragma unroll
            for (int f = 0; f < 4; ++f) {
                f32x4 d = __builtin_amdgcn_mfma_f32_16x16x32_bf16(a[f], b, zero4, 0, 0, 0);
#pragma unroll
                for (int r = 0; r < 4; ++r) m[f][r] = fmaxf(m[f][r], d[r]);
            }
        }
#pragma unroll
        for (int f = 0; f < 4; ++f)
#pragma unroll
            for (int r = 0; r < 4; ++r) {
                float v = m[f][r];
#pragma unroll
                for (int s = 1; s < 16; s <<= 1) v = fmaxf(v, __shfl_xor(v, s));
                if (col == 0) lf[wave * 64 + f * 16 + quad * 4 + r] = v;
            }
        __syncthreads();
        pmax[(size_t)y * NTOK + x * 256 + t] = lf[t];
    }
    gbar(2, arrive, gen);

    // ---------------- phase 2: rescan vs gmax-eps + exact fp32 rescore -------
    {
        int tok0 = x * 256 + t;
        float mx = -1e30f;
#pragma unroll
        for (int ch = 0; ch < NCHUNK; ++ch)       // coalesced column reads
            mx = fmaxf(mx, pmax[(size_t)ch * NTOK + tok0]);
        lf[t] = mx - EPSF;
    }
    __syncthreads();
    float thr[4][4];
#pragma unroll
    for (int f = 0; f < 4; ++f)
#pragma unroll
        for (int r = 0; r < 4; ++r)
            thr[f][r] = lf[wave * 64 + f * 16 + quad * 4 + r];

    for (int i = 0; i < 2; ++i) {
        int y = grp * 2 + i, kbase = y * CHUNK;
        __syncthreads();                          // lbs reuse guard
        {
            const float4* src = (const float4*)(ebf + (size_t)kbase * CDIM);
            float4* dst = (float4*)lbs;
#pragma unroll
            for (int j = 0; j < 4; ++j) dst[t + j * 256] = src[t + j * 256];
        }
        __syncthreads();
        for (int tt = 0; tt < TILES; ++tt) {
            bf16x8 b = bl[(tt * 16 + col) * 4 + quad];
#pragma unroll
            for (int f = 0; f < 4; ++f) {
                f32x4 d = __builtin_amdgcn_mfma_f32_16x16x32_bf16(a[f], b, zero4, 0, 0, 0);
#pragma unroll
                for (int r = 0; r < 4; ++r) {
                    if (d[r] >= thr[f][r]) {      // rare: ~1.05/token total
                        int tok = wtok + f * 16 + quad * 4 + r;
                        int code = kbase + tt * 16 + col;
                        const float* zp = zn + (size_t)tok * CDIM;
                        const float* ep = emb + (size_t)code * CDIM;
                        float a0 = 0.f, a1 = 0.f, a2 = 0.f, a3 = 0.f;
#pragma unroll
                        for (int j = 0; j < 8; ++j) {
                            a0 = __builtin_fmaf(zp[4 * j + 0], ep[4 * j + 0], a0);
                            a1 = __builtin_fmaf(zp[4 * j + 1], ep[4 * j + 1], a1);
                            a2 = __builtin_fmaf(zp[4 * j + 2], ep[4 * j + 2], a2);
                            a3 = __builtin_fmaf(zp[4 * j + 3], ep[4 * j + 3], a3);
                        }
                        float s = (a0 + a1) + (a2 + a3);
                        atomicMax(packed + tok,
                                  ((unsigned long long)fmap(s) << 13) |
                                  (unsigned long long)(8191 - code));
                    }
                }
            }
        }
    }
    gbar(3, arrive, gen);

    // ---------------- phase 3: z_q + loss (2 units) + ids/pos ----------------
    for (int i = 0; i < 2; ++i) {
        int unit = bid * 2 + i;
        int b3 = unit >> 5, c3 = unit & 31;
        int n = b3 * 256 + t;
        int id = 8191 - (int)(packed[n] & 8191ull);
        float ev = emb[(size_t)id * CDIM + c3];   // gather (L2)
        float zv = zn[(size_t)n * CDIM + c3];     // 128B-stride (L2)
        out[OUT_ZQ + ((size_t)b3 * CDIM + c3) * HW + t] = ev;  // coalesced
        float dd = ev - zv;
        float s = dd * dd;
#pragma unroll
        for (int off = 32; off > 0; off >>= 1) s += __shfl_down(s, off);
        if (lane == 0) ls4[wave] = s;
        __syncthreads();
        if (t == 0)
            atomicAdd(loss_part + (unit & 63), ls4[0] + ls4[1] + ls4[2] + ls4[3]);
        __syncthreads();                          // ls4 reuse guard
    }
    if (t < 16) {                                 // ids/pos: 16 tokens/block
        int n2 = bid * 16 + t;
        int id2 = 8191 - (int)(packed[n2] & 8191ull);
        ids[n2] = id2;
        out[OUT_IDS + n2] = (float)id2;
        pos[n2] = atomicAdd(bins + id2, 1);
    }
    gbar(4, arrive, gen);

    // ---------------- phase 4: bins exclusive scan (block 0) ----------------
    if (bid == 0) {
        int loc[32];
        int s = 0;
#pragma unroll
        for (int i = 0; i < 32; ++i) {            // local exclusive prefix
            loc[i] = s;
            s += bins[t * 32 + i];
        }
        int v = s;                                // wave-inclusive scan
#pragma unroll
        for (int sh = 1; sh < 64; sh <<= 1) {
            int o = __shfl_up(v, sh);
            if (lane >= sh) v += o;
        }
        if (lane == 63) wtot[wave] = v;
        __syncthreads();
        int wex = 0;
        for (int w = 0; w < wave; ++w) wex += wtot[w];
        int excl = wex + (v - s);
#pragma unroll
        for (int i = 0; i < 32; ++i) offs[t * 32 + i] = excl + loc[i];
    }
    gbar(5, arrive, gen);

    // ---------------- phase 5: counting-sort place ----------------
    if (t < 16) {
        int n = bid * 16 + t;
        sorted[offs[ids[n]] + pos[n]] = n;
    }
    gbar(6, arrive, gen);

    // ---------------- phase 6: EMA update (2 units) + loss finalize ----------
    if (bid == 0 && t < 64) {
        float lp = loss_part[t];
#pragma unroll
        for (int sh = 32; sh > 0; sh >>= 1) lp += __shfl_down(lp, sh);
        if (t == 0) out[OUT_LOSS] = lp * (1.0f / 262144.0f);
    }
    for (int i = 0; i < 2; ++i) {
        int idx = (bid * 2 + i) * 256 + t;
        int k = idx >> 5, c = idx & 31;
        int bi = bins[k];
        int off = offs[k];
        float tv = 0.f;
        for (int j = 0; j < bi; ++j) {            // avg 1 iter
            int n = sorted[off + j];
            tv += zn[(size_t)n * CDIM + c];       // coalesced 128B row
        }
        float bf = (float)bi;
        bool zero = (bi == 0);
        tv /= (zero ? 1.0f : bf);
        float ss = tv * tv;
#pragma unroll
        for (int s = 1; s < 32; s <<= 1) ss += __shfl_xor(ss, s);
        float d = fmaxf(sqrtf(ss), 1e-12f);
        float ew = emb[idx];
        float en = zero ? ew : (tv / d);
        float w = ew * DECAYF + (1.0f - DECAYF) * en;
        float ss2 = w * w;
#pragma unroll
        for (int s = 1; s < 32; s <<= 1) ss2 += __shfl_xor(ss2, s);
        float d2 = fmaxf(sqrtf(ss2), 1e-12f);
        out[OUT_EMB + idx] = w / d2;
        if (c == 0) out[OUT_CS + k] = cs[k] * DECAYF + (1.0f - DECAYF) * bf;
    }
}

extern "C" void kernel_launch(void* const* d_in, const int* in_sizes, int n_in,
                              void* d_out, int out_size, void* d_ws, size_t ws_size,
                              hipStream_t stream) {
    const float* z   = (const float*)d_in[0];   // [32,32,16,16]
    const float* emb = (const float*)d_in[1];   // [8192,32]
    const float* cs  = (const float*)d_in[2];   // [8192]
    float* out = (float*)d_out;
    char* ws = (char*)d_ws;

    float* zn                  = (float*)(ws + WS_ZN);
    unsigned short* znbf       = (unsigned short*)(ws + WS_ZNBF);
    unsigned short* ebf        = (unsigned short*)(ws + WS_EBF);
    float* pmax                = (float*)(ws + WS_PMAX);
    unsigned long long* packed = (unsigned long long*)(ws + WS_PACK);
    int* bins                  = (int*)(ws + WS_BINS);
    float* loss_part           = (float*)(ws + WS_LOSSP);
    int* ids                   = (int*)(ws + WS_IDS);
    int* pos                   = (int*)(ws + WS_POS);
    int* offs                  = (int*)(ws + WS_OFFS);
    int* sorted                = (int*)(ws + WS_SORTED);
    int* arrive                = (int*)(ws + WS_ARRIVE);
    int* gen                   = (int*)(ws + WS_GEN);

    k_all<<<dim3(NBLK), 256, 0, stream>>>(z, emb, cs, out, zn, znbf, ebf, pmax,
                                          packed, bins, loss_part, ids, pos,
                                          offs, sorted, arrive, gen);
}

// Round 15
// 142.914 us; speedup vs baseline: 4.2553x; 4.2553x over previous
//
#include <hip/hip_runtime.h>

// NormEMAVectorQuantizer on MI355X (gfx950)
// N=8192 tokens, C=32, K=8192 codes, B=32, H*W=256.
// R15: block-local argmax -> NO cross-block exchange (R14's grid barrier
// cost ~90us each; R12's two-sweep cost 3 launches + pmax/packed traffic).
// k_argmax: 512 blocks x 16 tokens; 4 waves split the 8192 codes (2048
// each), streaming B-frags from L2-resident ebf (512KB). Pass 1: bf16-MFMA
// running max -> LDS combine -> per-token gmax. Pass 2: recompute MFMA,
// qualify >= gmax-eps, inline exact fp32 rescore -> LDS u64 key max.
// Epilogue: ids/pos + z_q gather + loss partials, all in-block.
// Certificate: bf16 dot err <= 2*2^-9 = 0.0078 < eps=0.01 for unit rows ->
// every possible fp32 argmax (incl. ties) is exact-rescored; (8191-code)
// key = numpy lowest-index tie-break. Dense MFMA pass-2 retained (R8-R11
// sparse row-gather variants all lost to L1 thrash).
// Pipeline: prep+zero | argmax | scanplace | update  (4 dispatches, was 7).
//
// Outputs (float32, concatenated):
//   [0 .. 262144)        z_q_out [B,C,H,W]
//   [262144]             loss (scalar)
//   [262145 .. 270337)   token_ids [B,H,W] as float
//   [270337 .. 532481)   new_embedding [K,C]
//   [532481 .. 540673)   new_cluster_sizes [K]

#define NTOK   8192
#define NCODE  8192
#define CDIM   32
#define HW     256
#define DECAYF 0.99f
#define EPSF   0.01f

#define OUT_ZQ   0
#define OUT_LOSS 262144
#define OUT_IDS  262145
#define OUT_EMB  270337
#define OUT_CS   532481

// workspace byte offsets
#define WS_ZN     0u        // zn row-major [N,C] f32   = 1048576
#define WS_ZNBF   1048576u  // bf16 [N,C]               = 524288
#define WS_EBF    1572864u  // bf16 [K,C]               = 524288
#define WS_BINS   2097152u  // i32 [K]                  = 32768
#define WS_LOSSP  2129920u  // f32 [64]                 = 256
#define WS_IDS    2130176u  // i32 [N]
#define WS_POS    2162944u  // i32 [N]
#define WS_OFFS   2195712u  // i32 [K]
#define WS_SORTED 2228480u  // i32 [N]   (end 2261248)

typedef __attribute__((ext_vector_type(8))) short bf16x8;
typedef __attribute__((ext_vector_type(4))) float f32x4;

__device__ inline unsigned short f2bf(float x) {
    unsigned u = __float_as_uint(x);
    return (unsigned short)((u + 0x7FFFu + ((u >> 16) & 1u)) >> 16);
}
__device__ inline unsigned fmap(float s) {   // monotonic f32 -> u32
    unsigned u = __float_as_uint(s);
    return (u & 0x80000000u) ? ~u : (u | 0x80000000u);
}

// -------- Kernel A: prep (norm + bf16) + zero bins/loss_part -------------------
__global__ __launch_bounds__(256) void k_prep(const float* __restrict__ z,
                                              const float* __restrict__ emb,
                                              float* __restrict__ zn,
                                              unsigned short* __restrict__ znbf,
                                              unsigned short* __restrict__ ebf,
                                              int* __restrict__ bins,
                                              float* __restrict__ loss_part) {
    int bid = blockIdx.x, t = threadIdx.x;
    if (bid < 32) {                               // token norm -> zn, znbf
        int n = bid * 256 + t;
        int b = n >> 8, hw = n & 255;
        const float* zp = z + (size_t)b * (CDIM * HW) + hw;
        float v[CDIM];
        float ss = 0.f;
#pragma unroll
        for (int c = 0; c < CDIM; ++c) {
            float tv = zp[c * HW];                // coalesced per c
            v[c] = tv;
            ss += tv * tv;
        }
        float d = fmaxf(sqrtf(ss), 1e-12f);
        float* o = zn + (size_t)n * CDIM;
        unsigned short* ob = znbf + (size_t)n * CDIM;
#pragma unroll
        for (int c = 0; c < CDIM; ++c) {
            float tv = v[c] / d;
            o[c] = tv;
            ob[c] = f2bf(tv);
        }
    } else if (bid < 160) {                       // emb -> ebf
        int base = (bid - 32) * 2048 + t * 8;
        const float4* s = (const float4*)(emb + base);
        float4 x4 = s[0], y4 = s[1];
        ushort4 u0 = {f2bf(x4.x), f2bf(x4.y), f2bf(x4.z), f2bf(x4.w)};
        ushort4 u1 = {f2bf(y4.x), f2bf(y4.y), f2bf(y4.z), f2bf(y4.w)};
        *(ushort4*)(ebf + base) = u0;
        *(ushort4*)(ebf + base + 4) = u1;
    } else if (bid < 164) {                       // zero bins
        int base = (bid - 160) * 2048 + t;
#pragma unroll
        for (int j = 0; j < 8; ++j) bins[base + j * 256] = 0;
    } else {                                      // bid==164: zero loss_part
        if (t < 64) loss_part[t] = 0.f;
    }
}

// -------- Kernel B: block-local argmax + z_q + loss (the whole select path) ----
// 512 blocks x 256 thr. Block owns 16 tokens; wave w scans codes
// [w*2048,(w+1)*2048) with 128 MFMA, B-frags streamed from L2-resident ebf.
__global__ __launch_bounds__(256) void k_argmax(const unsigned short* __restrict__ znbf,
                                                const unsigned short* __restrict__ ebf,
                                                const float* __restrict__ zn,
                                                const float* __restrict__ emb,
                                                int* __restrict__ bins,
                                                int* __restrict__ ids,
                                                int* __restrict__ pos,
                                                float* __restrict__ out,
                                                float* __restrict__ loss_part) {
    __shared__ float gm[4][16];                   // per-wave token maxima
    __shared__ float thr[16];
    __shared__ unsigned long long bk[16];
    __shared__ int sid[16];
    __shared__ float ls4[4];

    int blk = blockIdx.x, t = threadIdx.x;
    int wave = t >> 6, lane = t & 63;
    int col = lane & 15, quad = lane >> 4;
    int tok0 = blk * 16;

    // A-frag: the block's 16 tokens (same for all 4 waves)
    bf16x8 a = *(const bf16x8*)(znbf + (size_t)(tok0 + col) * CDIM + quad * 8);

    const f32x4 zero4 = {0.f, 0.f, 0.f, 0.f};
    int wbase = wave * 2048;                      // this wave's code range

    // ---- pass 1: running max over 128 tiles ----
    float m0 = -1e30f, m1 = -1e30f, m2 = -1e30f, m3 = -1e30f;
#pragma unroll 4
    for (int tt = 0; tt < 128; ++tt) {
        int code = wbase + tt * 16 + col;
        bf16x8 b = *(const bf16x8*)(ebf + (size_t)code * CDIM + quad * 8);
        f32x4 d = __builtin_amdgcn_mfma_f32_16x16x32_bf16(a, b, zero4, 0, 0, 0);
        m0 = fmaxf(m0, d[0]); m1 = fmaxf(m1, d[1]);
        m2 = fmaxf(m2, d[2]); m3 = fmaxf(m3, d[3]);
    }
    // cross-col reduce (16 lanes sharing quad), then LDS combine over waves
    {
        float mm[4] = {m0, m1, m2, m3};
#pragma unroll
        for (int r = 0; r < 4; ++r) {
            float v = mm[r];
#pragma unroll
            for (int s = 1; s < 16; s <<= 1) v = fmaxf(v, __shfl_xor(v, s));
            if (col == 0) gm[wave][quad * 4 + r] = v;
        }
    }
    if (t < 16) bk[t] = 0ull;
    __syncthreads();
    if (t < 16)
        thr[t] = fmaxf(fmaxf(gm[0][t], gm[1][t]), fmaxf(gm[2][t], gm[3][t])) - EPSF;
    __syncthreads();

    float th0 = thr[quad * 4 + 0], th1 = thr[quad * 4 + 1];
    float th2 = thr[quad * 4 + 2], th3 = thr[quad * 4 + 3];

    // ---- pass 2: recompute, qualify, exact fp32 rescore -> LDS key max ----
#pragma unroll 4
    for (int tt = 0; tt < 128; ++tt) {
        int code = wbase + tt * 16 + col;
        bf16x8 b = *(const bf16x8*)(ebf + (size_t)code * CDIM + quad * 8);
        f32x4 d = __builtin_amdgcn_mfma_f32_16x16x32_bf16(a, b, zero4, 0, 0, 0);
#pragma unroll
        for (int r = 0; r < 4; ++r) {
            float dv = d[r];
            float tv = (r == 0) ? th0 : (r == 1) ? th1 : (r == 2) ? th2 : th3;
            if (dv >= tv) {                       // rare: ~1.05/token total
                int tl = quad * 4 + r;
                const float* zp = zn + (size_t)(tok0 + tl) * CDIM;
                const float* ep = emb + (size_t)code * CDIM;
                float a0 = 0.f, a1 = 0.f, a2 = 0.f, a3 = 0.f;
#pragma unroll
                for (int j = 0; j < 8; ++j) {
                    a0 = __builtin_fmaf(zp[4 * j + 0], ep[4 * j + 0], a0);
                    a1 = __builtin_fmaf(zp[4 * j + 1], ep[4 * j + 1], a1);
                    a2 = __builtin_fmaf(zp[4 * j + 2], ep[4 * j + 2], a2);
                    a3 = __builtin_fmaf(zp[4 * j + 3], ep[4 * j + 3], a3);
                }
                float s = (a0 + a1) + (a2 + a3);
                unsigned long long key = ((unsigned long long)fmap(s) << 13) |
                                         (unsigned long long)(8191 - code);
                atomicMax(&bk[tl], key);          // LDS atomic, rare
            }
        }
    }
    __syncthreads();

    // ---- epilogue: ids/pos ----
    if (t < 16) {
        int id = 8191 - (int)(bk[t] & 8191ull);
        sid[t] = id;
        int n = tok0 + t;
        ids[n] = id;
        out[OUT_IDS + n] = (float)id;
        pos[n] = atomicAdd(bins + id, 1);         // 8192 scattered atomics total
    }
    __syncthreads();

    // ---- z_q gather + transpose-out + loss ----
    float s = 0.f;
#pragma unroll
    for (int i = 0; i < 2; ++i) {
        int tl = i * 8 + (t >> 5);                // token-local 0..15
        int c = t & 31;
        int n = tok0 + tl;
        int id = sid[tl];
        float ev = emb[(size_t)id * CDIM + c];    // <=16 rows, L1-resident
        float zv = zn[(size_t)n * CDIM + c];      // coalesced row reads
        int b = n >> 8, hw = n & 255;
        out[OUT_ZQ + ((size_t)b * CDIM + c) * HW + hw] = ev;
        float dd = ev - zv;
        s += dd * dd;
    }
#pragma unroll
    for (int off = 32; off > 0; off >>= 1) s += __shfl_down(s, off);
    if (lane == 0) ls4[wave] = s;
    __syncthreads();
    if (t == 0)
        atomicAdd(loss_part + (blk & 63), ls4[0] + ls4[1] + ls4[2] + ls4[3]);
}

// -------- Kernel S: single-block scan of bins (wave-shuffle) + place sorted ----
__global__ __launch_bounds__(1024) void k_scanplace(const int* __restrict__ bins,
                                                    const int* __restrict__ ids,
                                                    const int* __restrict__ pos,
                                                    int* __restrict__ offs,
                                                    int* __restrict__ sorted) {
    __shared__ int wtot[16], wexcl[16];
    int t = threadIdx.x;
    int lane = t & 63, wid = t >> 6;
    int loc[8];
    int s = 0;
#pragma unroll
    for (int i = 0; i < 8; ++i) {                 // local exclusive prefix
        loc[i] = s;
        s += bins[t * 8 + i];
    }
    int v = s;                                    // wave-inclusive scan
#pragma unroll
    for (int sh = 1; sh < 64; sh <<= 1) {
        int o = __shfl_up(v, sh);
        if (lane >= sh) v += o;
    }
    if (lane == 63) wtot[wid] = v;
    __syncthreads();
    if (t < 16) {                                 // scan 16 wave totals
        int w = wtot[t];
        int iv = w;
#pragma unroll
        for (int sh = 1; sh < 16; sh <<= 1) {
            int o = __shfl_up(iv, sh);
            if (t >= sh) iv += o;
        }
        wexcl[t] = iv - w;
    }
    __syncthreads();
    int excl = wexcl[wid] + (v - s);              // global exclusive for thread
#pragma unroll
    for (int i = 0; i < 8; ++i) offs[t * 8 + i] = excl + loc[i];
    __syncthreads();
    for (int n = t; n < NTOK; n += 1024)
        sorted[offs[ids[n]] + pos[n]] = n;
}

// -------- Kernel F: EMA update via segment gather + renormalize + loss ---------
__global__ __launch_bounds__(256) void k_update(const float* __restrict__ zn,
                                                const float* __restrict__ emb,
                                                const float* __restrict__ cs,
                                                const int* __restrict__ bins,
                                                const int* __restrict__ offs,
                                                const int* __restrict__ sorted,
                                                const float* __restrict__ loss_part,
                                                float* __restrict__ out) {
    int idx = blockIdx.x * 256 + threadIdx.x;
    if (blockIdx.x == 0 && threadIdx.x < 64) {    // loss finalize (wave 0)
        float lp = loss_part[threadIdx.x];
#pragma unroll
        for (int sh = 32; sh > 0; sh >>= 1) lp += __shfl_down(lp, sh);
        if (threadIdx.x == 0) out[OUT_LOSS] = lp * (1.0f / 262144.0f);
    }
    int k = idx >> 5, c = idx & 31;
    int bi = bins[k];
    int off = offs[k];
    float t = 0.f;
    for (int i = 0; i < bi; ++i) {                // avg 1 iter
        int n = sorted[off + i];
        t += zn[(size_t)n * CDIM + c];            // coalesced 128B row
    }
    float bf = (float)bi;
    bool zero = (bi == 0);
    t /= (zero ? 1.0f : bf);
    float ss = t * t;
#pragma unroll
    for (int s = 1; s < 32; s <<= 1) ss += __shfl_xor(ss, s);
    float d = fmaxf(sqrtf(ss), 1e-12f);
    float ew = emb[idx];
    float en = zero ? ew : (t / d);
    float w = ew * DECAYF + (1.0f - DECAYF) * en;
    float ss2 = w * w;
#pragma unroll
    for (int s = 1; s < 32; s <<= 1) ss2 += __shfl_xor(ss2, s);
    float d2 = fmaxf(sqrtf(ss2), 1e-12f);
    out[OUT_EMB + idx] = w / d2;
    if (c == 0) out[OUT_CS + k] = cs[k] * DECAYF + (1.0f - DECAYF) * bf;
}

extern "C" void kernel_launch(void* const* d_in, const int* in_sizes, int n_in,
                              void* d_out, int out_size, void* d_ws, size_t ws_size,
                              hipStream_t stream) {
    const float* z   = (const float*)d_in[0];   // [32,32,16,16]
    const float* emb = (const float*)d_in[1];   // [8192,32]
    const float* cs  = (const float*)d_in[2];   // [8192]
    float* out = (float*)d_out;
    char* ws = (char*)d_ws;

    float* zn            = (float*)(ws + WS_ZN);
    unsigned short* znbf = (unsigned short*)(ws + WS_ZNBF);
    unsigned short* ebf  = (unsigned short*)(ws + WS_EBF);
    int* bins            = (int*)(ws + WS_BINS);
    float* loss_part     = (float*)(ws + WS_LOSSP);
    int* ids             = (int*)(ws + WS_IDS);
    int* pos             = (int*)(ws + WS_POS);
    int* offs            = (int*)(ws + WS_OFFS);
    int* sorted          = (int*)(ws + WS_SORTED);

    k_prep<<<dim3(165), 256, 0, stream>>>(z, emb, zn, znbf, ebf, bins, loss_part);
    k_argmax<<<dim3(NTOK / 16), 256, 0, stream>>>(znbf, ebf, zn, emb, bins, ids,
                                                  pos, out, loss_part);
    k_scanplace<<<dim3(1), 1024, 0, stream>>>(bins, ids, pos, offs, sorted);
    k_update<<<dim3(1024), 256, 0, stream>>>(zn, emb, cs, bins, offs, sorted,
                                             loss_part, out);
}